// Round 5
// baseline (1701.286 us; speedup 1.0000x reference)
//
#include <hip/hip_runtime.h>

// MHA forward: B=2, S=2048, D=1024, H=16, HD=64.
// ROUND 4 DIAGNOSIS: d_out is FLOAT32 (reference's output dtype), not bf16.
// Rounds 2-4 wrote packed bf16 into an f32 buffer -> deterministic garbage
// identical across three independent implementations (error 1.738281 each
// time). The math itself was verified by that three-way agreement.
//
// Pipeline (tiled, f32 accumulation everywhere):
//   gemm_nt<1> x3 : Q/K/V = x @ W^T + b -> (B,H,S,HD) in ws
//   attn_fwd      : flash-style causal attention -> (B,S,D) in ws
//   gemm_nt<0>    : out = attn @ Wp^T + bp -> d_out (FLOAT32)
// Intermediates: f32 if ws_size >= 64MB, else bf16 (both paths same math).

#define BB  2
#define SS  2048
#define DD  1024
#define HH  16
#define HDD 64

#define MASKED_F (-1.0e30f)

__device__ __forceinline__ float bf2f(ushort u) {
    return __uint_as_float(((unsigned)u) << 16);
}
__device__ __forceinline__ ushort f2bf(float f) {  // RNE
    unsigned u = __float_as_uint(f);
    u += 0x7fffu + ((u >> 16) & 1u);
    return (ushort)(u >> 16);
}

// generic elem conversions (overload-dispatched)
__device__ __forceinline__ float loadT(const float* p) { return *p; }
__device__ __forceinline__ float loadT(const ushort* p) { return bf2f(*p); }
__device__ __forceinline__ void storeT(float* p, float v) { *p = v; }
__device__ __forceinline__ void storeT(ushort* p, float v) { *p = f2bf(v); }

// 8-element contiguous vector loads -> float[8]
__device__ __forceinline__ void load8(const float* p, float* d) {
    const float4 a = ((const float4*)p)[0];
    const float4 b = ((const float4*)p)[1];
    d[0] = a.x; d[1] = a.y; d[2] = a.z; d[3] = a.w;
    d[4] = b.x; d[5] = b.y; d[6] = b.z; d[7] = b.w;
}
__device__ __forceinline__ void load8(const ushort* p, float* d) {
    const uint4 u = *(const uint4*)p;
    d[0] = __uint_as_float(u.x << 16);
    d[1] = __uint_as_float(u.x & 0xffff0000u);
    d[2] = __uint_as_float(u.y << 16);
    d[3] = __uint_as_float(u.y & 0xffff0000u);
    d[4] = __uint_as_float(u.z << 16);
    d[5] = __uint_as_float(u.z & 0xffff0000u);
    d[6] = __uint_as_float(u.w << 16);
    d[7] = __uint_as_float(u.w & 0xffff0000u);
}

// C[m,n] = sum_k A[m,k] * W[n,k] + bias[n]
// A: (M x Kdim) TA row-major; W: (N x Kdim) f32 row-major; bias f32.
// QKV_LAYOUT==1: out[((b*H+h)*S+s)*HD+hd]; else out[m*DD+n]. out dtype TO.
template <int QKV_LAYOUT, typename TA, typename TO>
__global__ __launch_bounds__(256) void gemm_nt(const TA* __restrict__ A,
                                               const float* __restrict__ W,
                                               const float* __restrict__ bias,
                                               TO* __restrict__ out,
                                               int Kdim) {
    __shared__ float As[64][33];
    __shared__ float Ws[64][33];
    const int tid = threadIdx.x;
    const int bm = blockIdx.x * 64;
    const int bn = blockIdx.y * 64;
    const int ty = tid >> 4, tx = tid & 15;
    const int lr = tid >> 2;        // load row 0..63
    const int lc = (tid & 3) * 8;   // load col, 8 elems/thread

    float acc[4][4] = {};

    for (int k0 = 0; k0 < Kdim; k0 += 32) {
        float ta[8], tw[8];
        load8(A + (size_t)(bm + lr) * Kdim + k0 + lc, ta);
        load8(W + (size_t)(bn + lr) * Kdim + k0 + lc, tw);
#pragma unroll
        for (int i = 0; i < 8; ++i) As[lr][lc + i] = ta[i];
#pragma unroll
        for (int i = 0; i < 8; ++i) Ws[lr][lc + i] = tw[i];
        __syncthreads();
#pragma unroll
        for (int kk = 0; kk < 32; ++kk) {
            float a[4], w[4];
#pragma unroll
            for (int i = 0; i < 4; ++i) a[i] = As[ty * 4 + i][kk];
#pragma unroll
            for (int j = 0; j < 4; ++j) w[j] = Ws[tx * 4 + j][kk];
#pragma unroll
            for (int i = 0; i < 4; ++i)
#pragma unroll
                for (int j = 0; j < 4; ++j) acc[i][j] += a[i] * w[j];
        }
        __syncthreads();
    }

#pragma unroll
    for (int i = 0; i < 4; ++i) {
        const int m = bm + ty * 4 + i;
#pragma unroll
        for (int j = 0; j < 4; ++j) {
            const int n = bn + tx * 4 + j;
            const float v = acc[i][j] + bias[n];
            size_t oidx;
            if (QKV_LAYOUT) {
                const int b = m >> 11, s = m & 2047, h = n >> 6, hd = n & 63;
                oidx = (((size_t)(b * HH + h) * SS) + s) * HDD + hd;
            } else {
                oidx = (size_t)m * DD + n;
            }
            storeT(out + oidx, v);
        }
    }
}

// Flash-style causal attention. Q,K,V: (B*H, S, HD) TI; Q scaled 1/8 on load.
// One block = one (b,h) + 64 query rows; k-tiles <= q-tile. Out: (B,S,D) TI.
template <typename TI>
__global__ __launch_bounds__(256) void attn_fwd(const TI* __restrict__ Q,
                                                const TI* __restrict__ K,
                                                const TI* __restrict__ V,
                                                const int* __restrict__ am,
                                                TI* __restrict__ O) {
    __shared__ float Qs[64][65];
    __shared__ float KVs[64][65];
    __shared__ float Ps[64][65];
    __shared__ float m_s[64], l_s[64], alpha_s[64];
    __shared__ int amk_s[64];
    __shared__ int amq_s[64];

    const int tid = threadIdx.x;
    const int qt = blockIdx.x;  // 0..31
    const int bh = blockIdx.y;  // 0..31
    const int b = bh >> 4;
    const int h = bh & 15;
    const int ty = tid >> 4, tx = tid & 15;
    const int lr = tid >> 2;         // load row 0..63
    const int lc = (tid & 3) * 16;   // 16 elems/thread

    const size_t base = (size_t)bh * SS * HDD;

    {
        const TI* p = Q + base + (size_t)(qt * 64 + lr) * HDD + lc;
        float t0[8], t1[8];
        load8(p, t0);
        load8(p + 8, t1);
#pragma unroll
        for (int i = 0; i < 8; ++i) Qs[lr][lc + i] = t0[i] * 0.125f;
#pragma unroll
        for (int i = 0; i < 8; ++i) Qs[lr][lc + 8 + i] = t1[i] * 0.125f;
    }
    if (tid < 64) {
        m_s[tid] = MASKED_F;
        l_s[tid] = 0.f;
        alpha_s[tid] = 0.f;
        amq_s[tid] = am[b * SS + qt * 64 + tid];
    }
    float acc[4][4] = {};
    __syncthreads();

    for (int kt = 0; kt <= qt; ++kt) {
        {   // stage K tile
            const TI* p = K + base + (size_t)(kt * 64 + lr) * HDD + lc;
            load8(p, &KVs[lr][lc]);
            load8(p + 8, &KVs[lr][lc + 8]);
        }
        if (tid < 64) amk_s[tid] = am[b * SS + kt * 64 + tid];
        __syncthreads();

        {   // logits tile
            float s[4][4] = {};
#pragma unroll 4
            for (int c = 0; c < 64; ++c) {
                float a[4], w[4];
#pragma unroll
                for (int i = 0; i < 4; ++i) a[i] = Qs[ty * 4 + i][c];
#pragma unroll
                for (int j = 0; j < 4; ++j) w[j] = KVs[tx * 4 + j][c];
#pragma unroll
                for (int i = 0; i < 4; ++i)
#pragma unroll
                    for (int j = 0; j < 4; ++j) s[i][j] += a[i] * w[j];
            }
#pragma unroll
            for (int i = 0; i < 4; ++i)
#pragma unroll
                for (int j = 0; j < 4; ++j) {
                    const int q = ty * 4 + i, t = tx * 4 + j;
                    const int qg = qt * 64 + q, tg = kt * 64 + t;
                    const bool valid = (tg <= qg) && amk_s[t] && amq_s[q];
                    Ps[q][t] = valid ? s[i][j] : MASKED_F;
                }
        }
        __syncthreads();

        // online softmax: one thread per row (verified structure)
        if (tid < 64) {
            const int q = tid;
            const float m = m_s[q];
            float rm = MASKED_F;
#pragma unroll 8
            for (int t = 0; t < 64; ++t) rm = fmaxf(rm, Ps[q][t]);
            const float nm = fmaxf(m, rm);
            float sum = 0.f;
#pragma unroll 8
            for (int t = 0; t < 64; ++t) {
                const float p = __expf(Ps[q][t] - nm);
                Ps[q][t] = p;
                sum += p;
            }
            const float alpha = __expf(m - nm);
            m_s[q] = nm;
            l_s[q] = alpha * l_s[q] + sum;
            alpha_s[q] = alpha;
        }
        __syncthreads();

        {   // stage V tile (reuse KVs)
            const TI* p = V + base + (size_t)(kt * 64 + lr) * HDD + lc;
            load8(p, &KVs[lr][lc]);
            load8(p + 8, &KVs[lr][lc + 8]);
        }
        __syncthreads();

        {   // rescale O, accumulate P @ V
            float al[4];
#pragma unroll
            for (int i = 0; i < 4; ++i) al[i] = alpha_s[ty * 4 + i];
#pragma unroll
            for (int i = 0; i < 4; ++i)
#pragma unroll
                for (int j = 0; j < 4; ++j) acc[i][j] *= al[i];
#pragma unroll 4
            for (int t = 0; t < 64; ++t) {
                float p[4], vv[4];
#pragma unroll
                for (int i = 0; i < 4; ++i) p[i] = Ps[ty * 4 + i][t];
#pragma unroll
                for (int j = 0; j < 4; ++j) vv[j] = KVs[t][tx * 4 + j];
#pragma unroll
                for (int i = 0; i < 4; ++i)
#pragma unroll
                    for (int j = 0; j < 4; ++j) acc[i][j] += p[i] * vv[j];
            }
        }
        __syncthreads();
    }

#pragma unroll
    for (int i = 0; i < 4; ++i) {
        const int q = ty * 4 + i;
        const int s = qt * 64 + q;
        const float l = l_s[q];
        const float inv = (l > 0.f) ? 1.f / l : 0.f;
#pragma unroll
        for (int j = 0; j < 4; ++j) {
            const int hd = tx * 4 + j;
            storeT(O + (size_t)(b * SS + s) * DD + h * HDD + hd, acc[i][j] * inv);
        }
    }
}

template <typename TI>
static void run_pipeline(const float* x, const int* am,
                         const float* Wq, const float* bq,
                         const float* Wk, const float* bk,
                         const float* Wv, const float* bv,
                         const float* Wp, const float* bp,
                         float* out, void* d_ws, hipStream_t stream) {
    const size_t elems = (size_t)BB * HH * SS * HDD;  // 4M
    TI* q_ws = (TI*)d_ws;
    TI* k_ws = q_ws + elems;
    TI* v_ws = k_ws + elems;
    TI* a_ws = v_ws + elems;

    const dim3 gblock(256);
    const dim3 ggrid(BB * SS / 64, DD / 64);  // (64,16)

    gemm_nt<1, float, TI><<<ggrid, gblock, 0, stream>>>(x, Wq, bq, q_ws, DD);
    gemm_nt<1, float, TI><<<ggrid, gblock, 0, stream>>>(x, Wk, bk, k_ws, DD);
    gemm_nt<1, float, TI><<<ggrid, gblock, 0, stream>>>(x, Wv, bv, v_ws, DD);

    const dim3 agrid(SS / 64, BB * HH);  // (32,32)
    attn_fwd<TI><<<agrid, gblock, 0, stream>>>(q_ws, k_ws, v_ws, am, a_ws);

    gemm_nt<0, TI, float><<<ggrid, gblock, 0, stream>>>(a_ws, Wp, bp, out, DD);
}

extern "C" void kernel_launch(void* const* d_in, const int* in_sizes, int n_in,
                              void* d_out, int out_size, void* d_ws, size_t ws_size,
                              hipStream_t stream) {
    const float* x  = (const float*)d_in[0];
    const int*   am = (const int*)d_in[1];
    const float* Wq = (const float*)d_in[2];
    const float* bq = (const float*)d_in[3];
    const float* Wk = (const float*)d_in[4];
    const float* bk = (const float*)d_in[5];
    const float* Wv = (const float*)d_in[6];
    const float* bv = (const float*)d_in[7];
    const float* Wp = (const float*)d_in[8];
    const float* bp = (const float*)d_in[9];
    float* out = (float*)d_out;  // reference output dtype is FLOAT32

    const size_t elems = (size_t)BB * HH * SS * HDD;
    if (ws_size >= elems * 4 * sizeof(float)) {
        run_pipeline<float>(x, am, Wq, bq, Wk, bk, Wv, bv, Wp, bp, out, d_ws, stream);
    } else {
        run_pipeline<ushort>(x, am, Wq, bq, Wk, bk, Wv, bv, Wp, bp, out, d_ws, stream);
    }
}

// Round 6
// 314.705 us; speedup vs baseline: 5.4060x; 5.4060x over previous
//
#include <hip/hip_runtime.h>

// MHA forward: B=2, S=2048, D=1024, H=16, HD=64. Inputs f32, mask int32,
// OUTPUT f32 (round-4 diagnosis). Intermediates bf16 in ws (32 MB).
//
// Round 5: full MFMA pipeline (mfma_f32_16x16x32_bf16).
//   gemm_mfma<1> fused QKV : grid (32,8,3), 128x128 tiles, f32->bf16 staged
//   attn_mfma              : flash attention on MFMA, V transposed in LDS,
//                            P via wave-private LDS C->A layout transform
//   gemm_mfma<0> proj      : bf16 A, f32 out + bias
//
// Fragment layouts (learn_hip m89/m91/m120, gfx950):
//   A/B frag (8 bf16): element j -> [m|n = lane&15][k = (lane>>4)*8 + j]
//   C/D (4 f32):       reg r     -> [row = (lane>>4)*4 + r][col = lane&15]

#define BB 2
#define SS 2048
#define DD 1024
#define HH 16
#define HDD 64
#define NEG_BIG (-1.0e30f)

typedef __attribute__((ext_vector_type(8))) short short8;
typedef __attribute__((ext_vector_type(4))) float floatx4;

__device__ __forceinline__ ushort f2bf(float f) {  // RNE
    unsigned u = __float_as_uint(f);
    u += 0x7fffu + ((u >> 16) & 1u);
    return (ushort)(u >> 16);
}
__device__ __forceinline__ unsigned pk2(float a, float b) {
    return ((unsigned)f2bf(b) << 16) | (unsigned)f2bf(a);
}
__device__ __forceinline__ void storeT(float* p, float v) { *p = v; }
__device__ __forceinline__ void storeT(ushort* p, float v) { *p = f2bf(v); }

// load 16 contiguous elems as packed bf16 into 2x uint4
__device__ __forceinline__ void ld16_bf(const float* p, uint4* r) {
    const float4 f0 = ((const float4*)p)[0];
    const float4 f1 = ((const float4*)p)[1];
    const float4 f2 = ((const float4*)p)[2];
    const float4 f3 = ((const float4*)p)[3];
    r[0].x = pk2(f0.x, f0.y); r[0].y = pk2(f0.z, f0.w);
    r[0].z = pk2(f1.x, f1.y); r[0].w = pk2(f1.z, f1.w);
    r[1].x = pk2(f2.x, f2.y); r[1].y = pk2(f2.z, f2.w);
    r[1].z = pk2(f3.x, f3.y); r[1].w = pk2(f3.z, f3.w);
}
__device__ __forceinline__ void ld16_bf(const ushort* p, uint4* r) {
    r[0] = ((const uint4*)p)[0];
    r[1] = ((const uint4*)p)[1];
}

// C[m,n] = sum_k A[m,k]*W[n,k] + bias[n].  M=4096, N=1024, K=1024.
// 128x128 block tile, BK=32, 4 waves (2x2), 16 MFMA + 8 ds_read_b128 per
// wave per K-step. QKV=1: z in {0,1,2} selects W/bias/out, out bf16 in
// (B,H,S,HD). QKV=0: out f32 row-major.
template <int QKV, typename TA, typename TO>
__global__ __launch_bounds__(256) void gemm_mfma(
    const TA* __restrict__ A,
    const float* __restrict__ W0, const float* __restrict__ W1,
    const float* __restrict__ W2,
    const float* __restrict__ B0, const float* __restrict__ B1,
    const float* __restrict__ B2,
    TO* __restrict__ O0, TO* __restrict__ O1, TO* __restrict__ O2)
{
    __shared__ ushort As[128 * 40];
    __shared__ ushort Bs[128 * 40];
    __shared__ float bias_s[128];

    const float* W;
    const float* bias;
    TO* out;
    if (QKV) {
        const int z = blockIdx.z;
        W    = z == 0 ? W0 : (z == 1 ? W1 : W2);
        bias = z == 0 ? B0 : (z == 1 ? B1 : B2);
        out  = z == 0 ? O0 : (z == 1 ? O1 : O2);
    } else { W = W0; bias = B0; out = O0; }

    const int tid = threadIdx.x;
    const int bm = blockIdx.x * 128, bn = blockIdx.y * 128;
    const int wave = tid >> 6, lane = tid & 63, quad = lane >> 4, lm = lane & 15;
    const int wm = wave >> 1, wn = wave & 1;
    const int sr = tid >> 1, sc = (tid & 1) * 16;  // staging: row, col

    if (tid < 128) bias_s[tid] = bias[bn + tid];

    const TA* arow = A + (size_t)(bm + sr) * DD + sc;
    const float* wrow = W + (size_t)(bn + sr) * DD + sc;

    uint4 ra[2], rw[2];
    ld16_bf(arow, ra);
    ld16_bf(wrow, rw);

    const floatx4 zz = {0.f, 0.f, 0.f, 0.f};
    floatx4 acc[4][4];
#pragma unroll
    for (int i = 0; i < 4; ++i)
#pragma unroll
        for (int j = 0; j < 4; ++j) acc[i][j] = zz;

    for (int k0 = 0; k0 < DD; k0 += 32) {
        __syncthreads();
        *(uint4*)&As[sr * 40 + sc] = ra[0];
        *(uint4*)&As[sr * 40 + sc + 8] = ra[1];
        *(uint4*)&Bs[sr * 40 + sc] = rw[0];
        *(uint4*)&Bs[sr * 40 + sc + 8] = rw[1];
        __syncthreads();
        if (k0 + 32 < DD) {  // prefetch next tile under the MFMAs
            ld16_bf(arow + k0 + 32, ra);
            ld16_bf(wrow + k0 + 32, rw);
        }
        short8 af[4], bf[4];
#pragma unroll
        for (int i = 0; i < 4; ++i)
            af[i] = *(const short8*)&As[(wm * 64 + i * 16 + lm) * 40 + quad * 8];
#pragma unroll
        for (int j = 0; j < 4; ++j)
            bf[j] = *(const short8*)&Bs[(wn * 64 + j * 16 + lm) * 40 + quad * 8];
#pragma unroll
        for (int i = 0; i < 4; ++i)
#pragma unroll
            for (int j = 0; j < 4; ++j)
                acc[i][j] = __builtin_amdgcn_mfma_f32_16x16x32_bf16(
                    af[i], bf[j], acc[i][j], 0, 0, 0);
    }

#pragma unroll
    for (int i = 0; i < 4; ++i) {
#pragma unroll
        for (int j = 0; j < 4; ++j) {
            const int nl = wn * 64 + j * 16 + lm;
            const int n = bn + nl;
            const float bb = bias_s[nl];
#pragma unroll
            for (int r = 0; r < 4; ++r) {
                const int m = bm + wm * 64 + i * 16 + quad * 4 + r;
                const float v = acc[i][j][r] + bb;
                size_t oidx;
                if (QKV) {
                    const int b = m >> 11, s = m & 2047, h = n >> 6, hd = n & 63;
                    oidx = (((size_t)(b * HH + h) * SS) + s) * HDD + hd;
                } else {
                    oidx = (size_t)m * DD + n;
                }
                storeT(out + oidx, v);
            }
        }
    }
}

// MFMA flash attention. Q,K,V: (B*H,S,HD) bf16. One block = (b,h) + 64 q
// rows; 4 waves x 16 q rows. K tile [t][hd] (stride 72), V tile transposed
// [hd][t] (stride 72), P via wave-private LDS (stride 72). Out (B,S,D) bf16.
__global__ __launch_bounds__(256) void attn_mfma(
    const ushort* __restrict__ Q, const ushort* __restrict__ K,
    const ushort* __restrict__ V, const int* __restrict__ am,
    ushort* __restrict__ O)
{
    __shared__ ushort Ks[64 * 72];
    __shared__ ushort Vt[64 * 72];
    __shared__ ushort Ps[4][16 * 72];
    __shared__ int amq_s[64], amk_s[64];

    const int tid = threadIdx.x;
    const int wq = tid >> 6, lane = tid & 63, quad = lane >> 4, lm = lane & 15;
    const int qt = (int)(gridDim.x - 1 - blockIdx.x);  // big blocks first
    const int bh = blockIdx.y, b = bh >> 4, h = bh & 15;
    const size_t base = (size_t)bh * SS * HDD;

    if (tid < 64) amq_s[tid] = am[b * SS + qt * 64 + tid];

    // Q fragments (direct from global, rows = this wave's 16 q rows)
    const ushort* qp = Q + base + (size_t)(qt * 64 + wq * 16 + lm) * HDD + quad * 8;
    const short8 qf0 = *(const short8*)qp;
    const short8 qf1 = *(const short8*)(qp + 32);

    const floatx4 zz = {0.f, 0.f, 0.f, 0.f};
    floatx4 o_acc[4];
#pragma unroll
    for (int n2 = 0; n2 < 4; ++n2) o_acc[n2] = zz;
    float m_r[4], l_r[4];
#pragma unroll
    for (int r = 0; r < 4; ++r) { m_r[r] = NEG_BIG; l_r[r] = 0.f; }

    __syncthreads();
    int amq4[4];
#pragma unroll
    for (int r = 0; r < 4; ++r) amq4[r] = amq_s[wq * 16 + quad * 4 + r];

    const int rk = tid >> 2, ck = (tid & 3) * 16;  // K staging (flat-coalesced)
    const int tv = tid & 63, cg = tid >> 6;        // V staging (transpose-friendly)

    for (int kt = 0; kt <= qt; ++kt) {
        __syncthreads();  // previous tile fully consumed
        {   // stage K [t][hd]
            const ushort* kp = K + base + (size_t)(kt * 64 + rk) * HDD + ck;
            const uint4 u0 = ((const uint4*)kp)[0], u1 = ((const uint4*)kp)[1];
            *(uint4*)&Ks[rk * 72 + ck] = u0;
            *(uint4*)&Ks[rk * 72 + ck + 8] = u1;
        }
        {   // stage V transposed: Vt[hd][t]
            const ushort* vp = V + base + (size_t)(kt * 64 + tv) * HDD + cg * 16;
            const uint4 u0 = ((const uint4*)vp)[0], u1 = ((const uint4*)vp)[1];
            ushort tmp[16];
            *(uint4*)&tmp[0] = u0;
            *(uint4*)&tmp[8] = u1;
#pragma unroll
            for (int e = 0; e < 16; ++e) Vt[(cg * 16 + e) * 72 + tv] = tmp[e];
        }
        if (tid < 64) amk_s[tid] = am[b * SS + kt * 64 + tid];
        __syncthreads();

        // ---- S = Q K^T  (4 n-tiles of 16 t, K-dim 64 = 2 mfma steps) ----
        floatx4 s_acc[4];
#pragma unroll
        for (int nt = 0; nt < 4; ++nt) {
            const short8 kf0 = *(const short8*)&Ks[(nt * 16 + lm) * 72 + quad * 8];
            const short8 kf1 = *(const short8*)&Ks[(nt * 16 + lm) * 72 + 32 + quad * 8];
            floatx4 z = zz;
            z = __builtin_amdgcn_mfma_f32_16x16x32_bf16(qf0, kf0, z, 0, 0, 0);
            z = __builtin_amdgcn_mfma_f32_16x16x32_bf16(qf1, kf1, z, 0, 0, 0);
            s_acc[nt] = z;
        }

        int amk4[4];
#pragma unroll
        for (int nt = 0; nt < 4; ++nt) amk4[nt] = amk_s[nt * 16 + lm];

        // ---- mask + scale + online softmax (C/D layout) ----
        const bool diag = (kt == qt);
        float p[4][4], mx[4];
#pragma unroll
        for (int r = 0; r < 4; ++r) mx[r] = NEG_BIG;
#pragma unroll
        for (int nt = 0; nt < 4; ++nt) {
            const int tg = kt * 64 + nt * 16 + lm;
#pragma unroll
            for (int r = 0; r < 4; ++r) {
                const int qg = qt * 64 + wq * 16 + quad * 4 + r;
                float sv = s_acc[nt][r] * 0.125f;
                const bool ok = amk4[nt] && amq4[r] && (!diag || tg <= qg);
                sv = ok ? sv : NEG_BIG;
                p[nt][r] = sv;
                mx[r] = fmaxf(mx[r], sv);
            }
        }
#pragma unroll
        for (int r = 0; r < 4; ++r) {  // row-max across the 16 t-lanes
            mx[r] = fmaxf(mx[r], __shfl_xor(mx[r], 1));
            mx[r] = fmaxf(mx[r], __shfl_xor(mx[r], 2));
            mx[r] = fmaxf(mx[r], __shfl_xor(mx[r], 4));
            mx[r] = fmaxf(mx[r], __shfl_xor(mx[r], 8));
        }
        float alpha[4], rs[4];
#pragma unroll
        for (int r = 0; r < 4; ++r) {
            const float mn = fmaxf(m_r[r], mx[r]);
            alpha[r] = __expf(m_r[r] - mn);
            m_r[r] = mn;
            rs[r] = 0.f;
        }
#pragma unroll
        for (int nt = 0; nt < 4; ++nt)
#pragma unroll
            for (int r = 0; r < 4; ++r) {
                const float e = __expf(p[nt][r] - m_r[r]);
                p[nt][r] = e;
                rs[r] += e;
            }
#pragma unroll
        for (int r = 0; r < 4; ++r) {
            rs[r] += __shfl_xor(rs[r], 1);
            rs[r] += __shfl_xor(rs[r], 2);
            rs[r] += __shfl_xor(rs[r], 4);
            rs[r] += __shfl_xor(rs[r], 8);
            l_r[r] = alpha[r] * l_r[r] + rs[r];
        }
        {   // rescale O
            const floatx4 av = {alpha[0], alpha[1], alpha[2], alpha[3]};
#pragma unroll
            for (int n2 = 0; n2 < 4; ++n2) o_acc[n2] *= av;
        }

        // ---- P: C-layout -> A-layout via wave-private LDS ----
#pragma unroll
        for (int nt = 0; nt < 4; ++nt)
#pragma unroll
            for (int r = 0; r < 4; ++r)
                Ps[wq][(quad * 4 + r) * 72 + nt * 16 + lm] = f2bf(p[nt][r]);

        const short8 af0 = *(const short8*)&Ps[wq][lm * 72 + quad * 8];
        const short8 af1 = *(const short8*)&Ps[wq][lm * 72 + 32 + quad * 8];

        // ---- O += P V  (B-frag from transposed V) ----
#pragma unroll
        for (int n2 = 0; n2 < 4; ++n2) {
            const short8 vf0 = *(const short8*)&Vt[(n2 * 16 + lm) * 72 + quad * 8];
            const short8 vf1 = *(const short8*)&Vt[(n2 * 16 + lm) * 72 + 32 + quad * 8];
            o_acc[n2] = __builtin_amdgcn_mfma_f32_16x16x32_bf16(af0, vf0, o_acc[n2], 0, 0, 0);
            o_acc[n2] = __builtin_amdgcn_mfma_f32_16x16x32_bf16(af1, vf1, o_acc[n2], 0, 0, 0);
        }
    }

    // ---- epilogue: normalize, write (B,S,D) bf16 ----
    float inv[4];
#pragma unroll
    for (int r = 0; r < 4; ++r) inv[r] = l_r[r] > 0.f ? 1.f / l_r[r] : 0.f;
#pragma unroll
    for (int n2 = 0; n2 < 4; ++n2)
#pragma unroll
        for (int r = 0; r < 4; ++r) {
            const int s = qt * 64 + wq * 16 + quad * 4 + r;
            O[((size_t)(b * SS + s)) * DD + h * HDD + n2 * 16 + lm] =
                f2bf(o_acc[n2][r] * inv[r]);
        }
}

extern "C" void kernel_launch(void* const* d_in, const int* in_sizes, int n_in,
                              void* d_out, int out_size, void* d_ws, size_t ws_size,
                              hipStream_t stream) {
    const float* x  = (const float*)d_in[0];
    const int*   am = (const int*)d_in[1];
    const float* Wq = (const float*)d_in[2];
    const float* bq = (const float*)d_in[3];
    const float* Wk = (const float*)d_in[4];
    const float* bk = (const float*)d_in[5];
    const float* Wv = (const float*)d_in[6];
    const float* bv = (const float*)d_in[7];
    const float* Wp = (const float*)d_in[8];
    const float* bp = (const float*)d_in[9];
    float* out = (float*)d_out;

    const size_t elems = (size_t)BB * HH * SS * HDD;  // 4M
    ushort* q_ws = (ushort*)d_ws;
    ushort* k_ws = q_ws + elems;
    ushort* v_ws = k_ws + elems;
    ushort* a_ws = v_ws + elems;  // (B,S,D) bf16

    gemm_mfma<1, float, ushort><<<dim3(32, 8, 3), 256, 0, stream>>>(
        x, Wq, Wk, Wv, bq, bk, bv, q_ws, k_ws, v_ws);

    attn_mfma<<<dim3(SS / 64, BB * HH), 256, 0, stream>>>(q_ws, k_ws, v_ws, am, a_ws);

    gemm_mfma<0, ushort, float><<<dim3(32, 8, 1), 256, 0, stream>>>(
        a_ws, Wp, Wp, Wp, bp, bp, bp, out, out, out);
}